// Round 18
// baseline (181.090 us; speedup 1.0000x reference)
//
#include <hip/hip_runtime.h>

#define H 4
#define DIN 128
#define DOUT 64
#define EIN 16
#define EOUT 16
#define NEG_SLOPE 0.2f

typedef unsigned short ushortT;
typedef __attribute__((ext_vector_type(4))) short bf16x4;
typedef __attribute__((ext_vector_type(8))) short bf16x8;
typedef __attribute__((ext_vector_type(4))) float f32x4;

static __device__ __forceinline__ ushortT f2bf(float f) {
  unsigned x = __float_as_uint(f);
  unsigned r = (x + 0x7FFFu + ((x >> 16) & 1u)) >> 16;   // RNE
  return (ushortT)r;
}

static __device__ __forceinline__ bf16x4 pack4(float4 v) {
  bf16x4 r;
  r[0] = (short)f2bf(v.x);
  r[1] = (short)f2bf(v.y);
  r[2] = (short)f2bf(v.z);
  r[3] = (short)f2bf(v.w);
  return r;
}

static __device__ __forceinline__ bf16x8 pack8(float4 lo, float4 hi) {
  bf16x8 bb;
  bb[0] = (short)f2bf(lo.x); bb[1] = (short)f2bf(lo.y);
  bb[2] = (short)f2bf(lo.z); bb[3] = (short)f2bf(lo.w);
  bb[4] = (short)f2bf(hi.x); bb[5] = (short)f2bf(hi.y);
  bb[6] = (short)f2bf(hi.z); bb[7] = (short)f2bf(hi.w);
  return bb;
}

#if __has_builtin(__builtin_amdgcn_mfma_f32_16x16x16bf16_1k)
static __device__ __forceinline__ f32x4 mfma16(bf16x4 a, bf16x4 b, f32x4 c) {
  return __builtin_amdgcn_mfma_f32_16x16x16bf16_1k(a, b, c, 0, 0, 0);
}
#else
static __device__ __forceinline__ f32x4 mfma16(bf16x4 a, bf16x4 b, f32x4 c) {
  f32x4 d;
  asm volatile("v_mfma_f32_16x16x16_bf16 %0, %1, %2, %3"
               : "=v"(d) : "v"(a), "v"(b), "v"(c));
  return d;
}
#endif

static __device__ __forceinline__ f32x4 mfma32(bf16x8 a, bf16x8 b, f32x4 c) {
  return __builtin_amdgcn_mfma_f32_16x16x32_bf16(a, b, c, 0, 0, 0);
}

// ---- setup: prepack W_l + W_e into bf16 MFMA fragments --------------------
__global__ __launch_bounds__(256) void k_setup(const float* __restrict__ Wl,
                                               const float* __restrict__ att_l,
                                               const float* __restrict__ att_r,
                                               const float* __restrict__ We,
                                               const float* __restrict__ att_e,
                                               ushortT* __restrict__ Wlb,
                                               ushortT* __restrict__ Wfb,
                                               ushortT* __restrict__ Web) {
  int tid = threadIdx.x;
  if (blockIdx.x < 16) {
    int gid = blockIdx.x * 256 + tid;      // h*1024 + ct*256 + kt*64 + lane
    int h = gid >> 10, ct = (gid >> 8) & 3, kt = (gid >> 6) & 3, lane = gid & 63;
    int c16 = lane & 15, kg = lane >> 4;
    const float* wp = Wl + (size_t)(h * 64 + ct * 16 + c16) * DIN + kt * 32 + kg * 4;
    bf16x8 bb = pack8(*(const float4*)wp, *(const float4*)(wp + 16));
    *(bf16x8*)(Wlb + (size_t)gid * 8) = bb;
  } else {
    __shared__ float Wf[2][4][128];
    for (int it = 0; it < 4; ++it) {
      int id = it * 256 + tid;             // side*512 + h*128 + k
      int side = id >> 9, h = (id >> 7) & 3, k = id & 127;
      const float* att = side ? att_r : att_l;
      float s = 0.f;
      for (int c = 0; c < 64; ++c)
        s += Wl[(size_t)(h * 64 + c) * DIN + k] * att[h * 64 + c];
      Wf[side][h][k] = s;
    }
    __syncthreads();
    for (int it = 0; it < 4; ++it) {
      int fid = it * 256 + tid;            // h*256 + kt*64 + lane
      int h = fid >> 8, kt = (fid >> 6) & 3, lane = fid & 63;
      int c16 = lane & 15, kg = lane >> 4;
      bf16x8 bb = {};
      if (c16 < 2) {
        const float* p = &Wf[c16][h][kt * 32 + kg * 4];
        bb = pack8(*(const float4*)p, *(const float4*)(p + 16));
      }
      *(bf16x8*)(Wfb + (size_t)fid * 8) = bb;
    }
    if (tid < 64) {
      int lane = tid;
      int col = lane & 15, kg = lane >> 4;
#pragma unroll
      for (int ct = 0; ct < 4; ++ct) {
        float4 wv = *(const float4*)(We + (size_t)(ct * 16 + col) * 16 + kg * 4);
        *(bf16x4*)(Web + (size_t)(ct * 64 + lane) * 4) = pack4(wv);
      }
      float wf0 = 0.f, wf1 = 0.f, wf2 = 0.f, wf3 = 0.f;
      if (col < 4) {
#pragma unroll
        for (int c = 0; c < 16; ++c) {
          float av = att_e[col * 16 + c];
          float4 wv = *(const float4*)(We + (size_t)(col * 16 + c) * 16 + kg * 4);
          wf0 += wv.x * av; wf1 += wv.y * av;
          wf2 += wv.z * av; wf3 += wv.w * av;
        }
      }
      *(bf16x4*)(Web + (size_t)(4 * 64 + lane) * 4) =
          pack4(make_float4(wf0, wf1, wf2, wf3));
    }
  }
}

// ---- MEGA kernel: blocks [0,NBn) = node GEMM (+hist); [NBn,..) = edge GEMM
__global__ __launch_bounds__(256) void k_mega(const float* __restrict__ x,
                                              const ushortT* __restrict__ Wlb,
                                              const ushortT* __restrict__ Wfb,
                                              const float* __restrict__ ea,
                                              const ushortT* __restrict__ Web,
                                              const float* __restrict__ ebias,
                                              const int* __restrict__ eidst,
                                              int* __restrict__ cnt,
                                              ushortT* __restrict__ xlb,
                                              float* __restrict__ al,
                                              float* __restrict__ ar,
                                              float* __restrict__ eout,
                                              float* __restrict__ ae,
                                              int N, int E, int NBn) {
  __shared__ char smem[32 * 264 * 2];   // 16.9KB union
  int tid = threadIdx.x;
  int w = tid >> 6;
  int lane = tid & 63;

  if (blockIdx.x < NBn) {
    // ================= node projection =================
    ushortT (*Alds)[4][32][8] = (ushortT(*)[4][32][8])smem;
    ushortT* olds = (ushortT*)smem;     // [32][264]
    int c16 = lane & 15;
    int kg = lane >> 4;
    int m0 = blockIdx.x * 32;

    for (int f = tid; f < 32 * 32; f += 256) {
      int r = f >> 5, m = f & 31;
      int gr = m0 + r;
      float4 v = make_float4(0.f, 0.f, 0.f, 0.f);
      if (gr < N) v = *(const float4*)(x + (size_t)gr * DIN + m * 4);
      int kt = m >> 3, half = (m >> 2) & 1, kq = m & 3;
      int rs = r ^ kq ^ ((kt & 1) << 2);
      *(bf16x4*)&Alds[kt][kq][rs][half * 4] = pack4(v);
    }

    f32x4 acc[2][4];
    f32x4 accf[2];
#pragma unroll
    for (int rt = 0; rt < 2; ++rt) {
      accf[rt] = (f32x4){0.f, 0.f, 0.f, 0.f};
#pragma unroll
      for (int ct = 0; ct < 4; ++ct) acc[rt][ct] = (f32x4){0.f, 0.f, 0.f, 0.f};
    }

    __syncthreads();

    const bf16x8* WB = (const bf16x8*)Wlb;
    const bf16x8* WF = (const bf16x8*)Wfb;

#pragma unroll
    for (int kt = 0; kt < 4; ++kt) {
      bf16x8 afr[2];
#pragma unroll
      for (int rt = 0; rt < 2; ++rt) {
        int rs = (rt * 16 + c16) ^ kg ^ ((kt & 1) << 2);
        afr[rt] = *(const bf16x8*)&Alds[kt][kg][rs][0];
      }
#pragma unroll
      for (int ct = 0; ct < 4; ++ct) {
        bf16x8 b = WB[((w * 4 + ct) * 4 + kt) * 64 + lane];
        acc[0][ct] = mfma32(afr[0], b, acc[0][ct]);
        acc[1][ct] = mfma32(afr[1], b, acc[1][ct]);
      }
      bf16x8 bf = WF[(w * 4 + kt) * 64 + lane];
      accf[0] = mfma32(afr[0], bf, accf[0]);
      accf[1] = mfma32(afr[1], bf, accf[1]);
    }

    __syncthreads();   // reuse smem as out-tile

    if (c16 < 2) {
#pragma unroll
      for (int rt = 0; rt < 2; ++rt) {
#pragma unroll
        for (int reg = 0; reg < 4; ++reg) {
          int gr = m0 + rt * 16 + kg * 4 + reg;
          if (gr < N) {
            if (c16 == 0) al[(size_t)gr * H + w] = accf[rt][reg];
            else          ar[(size_t)gr * H + w] = accf[rt][reg];
          }
        }
      }
    }

#pragma unroll
    for (int rt = 0; rt < 2; ++rt) {
#pragma unroll
      for (int reg = 0; reg < 4; ++reg) {
        int r = rt * 16 + kg * 4 + reg;
#pragma unroll
        for (int ct = 0; ct < 4; ++ct)
          olds[r * 264 + (ct * 16 + c16) * 4 + w] = f2bf(acc[rt][ct][reg]);
      }
    }
    __syncthreads();

    for (int f = tid; f < 32 * 32; f += 256) {
      int r = f >> 5, ch = f & 31;
      int gr = m0 + r;
      if (gr < N) {
        uint4 v = *(const uint4*)&olds[r * 264 + ch * 8];
        *(uint4*)(xlb + (size_t)gr * 256 + ch * 8) = v;
      }
    }

    // fused degree histogram (grid-stride over node-part sub-grid)
    int total = NBn * 256;
    for (int e = blockIdx.x * 256 + tid; e < E; e += total)
      atomicAdd(&cnt[eidst[e]], 1);
  } else {
    // ================= edge GEMM (streaming) =================
    float (*alds)[4][68] = (float(*)[4][68])smem;   // [wave][head][edge]
    int col = lane & 15;
    int kg = lane >> 4;
    const bf16x4* WE = (const bf16x4*)Web;
    bf16x4 bfr0 = WE[0 * 64 + lane];
    bf16x4 bfr1 = WE[1 * 64 + lane];
    bf16x4 bfr2 = WE[2 * 64 + lane];
    bf16x4 bfr3 = WE[3 * 64 + lane];
    bf16x4 bfold = WE[4 * 64 + lane];
    float bias = ebias[col];
    int ebase = (blockIdx.x - NBn) * 256 + w * 64;

#pragma unroll
    for (int t = 0; t < 4; ++t) {
      int tb = ebase + t * 16;
      if (tb >= E) continue;
      float4 av = *(const float4*)(ea + (size_t)(tb + col) * EIN + kg * 4);
      bf16x4 afr = pack4(av);
      f32x4 z = {0.f, 0.f, 0.f, 0.f};
      f32x4 d0 = mfma16(afr, bfr0, z);
      f32x4 d1 = mfma16(afr, bfr1, z);
      f32x4 d2 = mfma16(afr, bfr2, z);
      f32x4 d3 = mfma16(afr, bfr3, z);
      f32x4 d4 = mfma16(afr, bfold, z);

#pragma unroll
      for (int reg = 0; reg < 4; ++reg) {
        float m = fmaxf(fmaxf(d0[reg], d1[reg]), fmaxf(d2[reg], d3[reg]));
        eout[(size_t)(tb + kg * 4 + reg) * EOUT + col] = fmaxf(m + bias, 0.f);
      }

      if (col < 4) {
#pragma unroll
        for (int reg = 0; reg < 4; ++reg)
          alds[w][col][t * 16 + kg * 4 + reg] = d4[reg];
      }
    }

    // coalesced alpha_e dump, 16B per lane (same-wave LDS, no barrier)
    int g = ebase + lane;
    if (g < E) {
      float4 a4 = make_float4(alds[w][0][lane], alds[w][1][lane],
                              alds[w][2][lane], alds[w][3][lane]);
      *(float4*)(ae + (size_t)g * H) = a4;
    }
  }
}

// ---------------- scans ----------------------------------------------------
__global__ __launch_bounds__(256) void k_scan1(const int* __restrict__ cnt,
                                               int* __restrict__ offs,
                                               int* __restrict__ bsum, int N) {
  __shared__ int s[256];
  int i = blockIdx.x * 256 + threadIdx.x;
  int v = (i < N) ? cnt[i] : 0;
  s[threadIdx.x] = v;
  __syncthreads();
  for (int off = 1; off < 256; off <<= 1) {
    int t = (threadIdx.x >= off) ? s[threadIdx.x - off] : 0;
    __syncthreads();
    s[threadIdx.x] += t;
    __syncthreads();
  }
  if (i < N) offs[i] = s[threadIdx.x] - v;
  if (threadIdx.x == 255) bsum[blockIdx.x] = s[255];
}

__global__ __launch_bounds__(256) void k_scan2(const int* __restrict__ bsum,
                                               int* __restrict__ boffs, int NB) {
  __shared__ int s[256];
  int v = (threadIdx.x < NB) ? bsum[threadIdx.x] : 0;
  s[threadIdx.x] = v;
  __syncthreads();
  for (int off = 1; off < 256; off <<= 1) {
    int t = (threadIdx.x >= off) ? s[threadIdx.x - off] : 0;
    __syncthreads();
    s[threadIdx.x] += t;
    __syncthreads();
  }
  if (threadIdx.x < NB) boffs[threadIdx.x] = s[threadIdx.x] - v;
}

__global__ __launch_bounds__(256) void k_scan3(int* __restrict__ offs,
                                               const int* __restrict__ boffs,
                                               int* __restrict__ cursor, int N) {
  int i = blockIdx.x * 256 + threadIdx.x;
  if (i < N) {
    int o = offs[i] + boffs[blockIdx.x];
    offs[i] = o;
    cursor[i] = o;
  }
}

// ---- scatter: 1 lane = 1 edge, 16B record {bf16 ex[4], src<<9, pad} -------
__global__ __launch_bounds__(256) void k_edgescatter(const int* __restrict__ ei,
                                                     const float* __restrict__ ae,
                                                     const float* __restrict__ al,
                                                     const float* __restrict__ ar,
                                                     int* __restrict__ cur,
                                                     uint4* __restrict__ rec, int E) {
  int e = blockIdx.x * 256 + threadIdx.x;
  if (e >= E) return;
  int sN = ei[e];
  int dN = ei[E + e];
  float4 ae4 = *(const float4*)(ae + (size_t)e * H);
  float4 a4 = *(const float4*)(al + (size_t)sN * H);
  float4 r4 = *(const float4*)(ar + (size_t)dN * H);
  float lg0 = a4.x + r4.x + ae4.x;
  float lg1 = a4.y + r4.y + ae4.y;
  float lg2 = a4.z + r4.z + ae4.z;
  float lg3 = a4.w + r4.w + ae4.w;
  lg0 = (lg0 >= 0.f) ? lg0 : NEG_SLOPE * lg0;
  lg1 = (lg1 >= 0.f) ? lg1 : NEG_SLOPE * lg1;
  lg2 = (lg2 >= 0.f) ? lg2 : NEG_SLOPE * lg2;
  lg3 = (lg3 >= 0.f) ? lg3 : NEG_SLOPE * lg3;
  int p = atomicAdd(&cur[dN], 1);
  unsigned ex01 = (unsigned)f2bf(__expf(lg0)) | ((unsigned)f2bf(__expf(lg1)) << 16);
  unsigned ex23 = (unsigned)f2bf(__expf(lg2)) | ((unsigned)f2bf(__expf(lg3)) << 16);
  uint4 v;
  v.x = ex01; v.y = ex23; v.z = ((unsigned)sN) << 9; v.w = 0;  // byte offset
  rec[p] = v;
}

// ------- aggregation: wave per node, 8-wide gather pipeline ----------------
__global__ __launch_bounds__(256) void k_agg(const char* __restrict__ xlbB,
                                             const uint4* __restrict__ rec,
                                             const int* __restrict__ offs,
                                             const int* __restrict__ cnt,
                                             const float* __restrict__ nbias,
                                             float* __restrict__ out, int N) {
  int wv = (blockIdx.x * 256 + threadIdx.x) >> 6;
  int lane = threadIdx.x & 63;
  if (wv >= N) return;
  int deg = cnt[wv];
  int start = offs[wv];
  int loff = lane * 8;
  float acc0 = 0.f, acc1 = 0.f, acc2 = 0.f, acc3 = 0.f;
  float s0 = 0.f, s1 = 0.f, s2 = 0.f, s3 = 0.f;

  int i = 0;
  for (; i + 7 < deg; i += 8) {
    unsigned zo[8], ex0[8], ex1[8];
#pragma unroll
    for (int j = 0; j < 8; ++j) {
      uint4 r = rec[start + i + j];
      ex0[j] = r.x; ex1[j] = r.y; zo[j] = r.z;
    }
    uint2 u[8];
#pragma unroll
    for (int j = 0; j < 8; ++j)
      u[j] = *(const uint2*)(xlbB + (size_t)zo[j] + loff);
#pragma unroll
    for (int j = 0; j < 8; ++j) {
      float e0 = __uint_as_float(ex0[j] << 16);
      float e1 = __uint_as_float(ex0[j] & 0xFFFF0000u);
      float e2 = __uint_as_float(ex1[j] << 16);
      float e3 = __uint_as_float(ex1[j] & 0xFFFF0000u);
      acc0 += e0 * __uint_as_float(u[j].x << 16);
      acc1 += e1 * __uint_as_float(u[j].x & 0xFFFF0000u);
      acc2 += e2 * __uint_as_float(u[j].y << 16);
      acc3 += e3 * __uint_as_float(u[j].y & 0xFFFF0000u);
      s0 += e0; s1 += e1; s2 += e2; s3 += e3;
    }
  }
  for (; i + 3 < deg; i += 4) {
    unsigned zo[4], ex0[4], ex1[4];
#pragma unroll
    for (int j = 0; j < 4; ++j) {
      uint4 r = rec[start + i + j];
      ex0[j] = r.x; ex1[j] = r.y; zo[j] = r.z;
    }
    uint2 u[4];
#pragma unroll
    for (int j = 0; j < 4; ++j)
      u[j] = *(const uint2*)(xlbB + (size_t)zo[j] + loff);
#pragma unroll
    for (int j = 0; j < 4; ++j) {
      float e0 = __uint_as_float(ex0[j] << 16);
      float e1 = __uint_as_float(ex0[j] & 0xFFFF0000u);
      float e2 = __uint_as_float(ex1[j] << 16);
      float e3 = __uint_as_float(ex1[j] & 0xFFFF0000u);
      acc0 += e0 * __uint_as_float(u[j].x << 16);
      acc1 += e1 * __uint_as_float(u[j].x & 0xFFFF0000u);
      acc2 += e2 * __uint_as_float(u[j].y << 16);
      acc3 += e3 * __uint_as_float(u[j].y & 0xFFFF0000u);
      s0 += e0; s1 += e1; s2 += e2; s3 += e3;
    }
  }
  for (; i < deg; ++i) {
    uint4 r = rec[start + i];
    uint2 u = *(const uint2*)(xlbB + (size_t)r.z + loff);
    float e0 = __uint_as_float(r.x << 16);
    float e1 = __uint_as_float(r.x & 0xFFFF0000u);
    float e2 = __uint_as_float(r.y << 16);
    float e3 = __uint_as_float(r.y & 0xFFFF0000u);
    acc0 += e0 * __uint_as_float(u.x << 16);
    acc1 += e1 * __uint_as_float(u.x & 0xFFFF0000u);
    acc2 += e2 * __uint_as_float(u.y << 16);
    acc3 += e3 * __uint_as_float(u.y & 0xFFFF0000u);
    s0 += e0; s1 += e1; s2 += e2; s3 += e3;
  }
  float best = acc0 / (s0 + 1e-16f);
  best = fmaxf(best, acc1 / (s1 + 1e-16f));
  best = fmaxf(best, acc2 / (s2 + 1e-16f));
  best = fmaxf(best, acc3 / (s3 + 1e-16f));
  out[(size_t)wv * DOUT + lane] = fmaxf(best + nbias[lane], 0.f);
}

// ---------------- launcher -------------------------------------------------
extern "C" void kernel_launch(void* const* d_in, const int* in_sizes, int n_in,
                              void* d_out, int out_size, void* d_ws, size_t ws_size,
                              hipStream_t stream) {
  const float* x     = (const float*)d_in[0];
  const float* ea    = (const float*)d_in[1];
  const int*   ei    = (const int*)d_in[2];
  const float* Wl    = (const float*)d_in[3];
  const float* We    = (const float*)d_in[4];
  const float* att_l = (const float*)d_in[5];
  const float* att_r = (const float*)d_in[6];
  const float* att_e = (const float*)d_in[7];
  const float* nbias = (const float*)d_in[8];
  const float* ebias = (const float*)d_in[9];

  int N = in_sizes[0] / DIN;
  int E = in_sizes[1] / EIN;

  float* out  = (float*)d_out;
  float* eout = (float*)d_out + (size_t)N * DOUT;

  char* w = (char*)d_ws;
  auto alloc = [&](size_t bytes) -> void* {
    void* p = (void*)w;
    w += (bytes + 255) & ~(size_t)255;
    return p;
  };
  ushortT* xlb = (ushortT*)alloc((size_t)N * 256 * 2);
  float* al    = (float*)alloc((size_t)N * H * 4);
  float* ar    = (float*)alloc((size_t)N * H * 4);
  ushortT* Wlb = (ushortT*)alloc(4096 * 8 * 2);
  ushortT* Wfb = (ushortT*)alloc(1024 * 8 * 2);
  ushortT* Web = (ushortT*)alloc(5 * 64 * 4 * 2);
  int* cnt     = (int*)alloc((size_t)N * 4);
  int* offs    = (int*)alloc((size_t)N * 4);
  int* cur     = (int*)alloc((size_t)N * 4);
  int* bsum    = (int*)alloc(256 * 4);
  int* boffs   = (int*)alloc(256 * 4);
  float* ae    = (float*)alloc((size_t)E * H * 4);
  uint4* rec   = (uint4*)alloc((size_t)E * 16);

  hipMemsetAsync(cnt, 0, (size_t)N * 4, stream);

  int NBn = (N + 31) / 32;          // 1563 node blocks
  int NBe = (E + 255) / 256;        // 3125 edge blocks

  k_setup<<<17, 256, 0, stream>>>(Wl, att_l, att_r, We, att_e, Wlb, Wfb, Web);
  k_mega<<<NBn + NBe, 256, 0, stream>>>(x, Wlb, Wfb, ea, Web, ebias, ei + E, cnt,
                                        xlb, al, ar, eout, ae, N, E, NBn);
  int NB = (N + 255) / 256;
  k_scan1<<<NB, 256, 0, stream>>>(cnt, offs, bsum, N);
  k_scan2<<<1, 256, 0, stream>>>(bsum, boffs, NB);
  k_scan3<<<NB, 256, 0, stream>>>(offs, boffs, cur, N);
  k_edgescatter<<<(E + 255) / 256, 256, 0, stream>>>(ei, ae, al, ar, cur, rec, E);
  k_agg<<<(N * 64 + 255) / 256, 256, 0, stream>>>((const char*)xlb, rec, offs, cnt,
                                                  nbias, out, N);
}

// Round 19
// 171.738 us; speedup vs baseline: 1.0545x; 1.0545x over previous
//
#include <hip/hip_runtime.h>

#define H 4
#define DIN 128
#define DOUT 64
#define EIN 16
#define EOUT 16
#define NEG_SLOPE 0.2f

typedef unsigned short ushortT;
typedef __attribute__((ext_vector_type(4))) short bf16x4;
typedef __attribute__((ext_vector_type(8))) short bf16x8;
typedef __attribute__((ext_vector_type(4))) float f32x4;

static __device__ __forceinline__ ushortT f2bf(float f) {
  unsigned x = __float_as_uint(f);
  unsigned r = (x + 0x7FFFu + ((x >> 16) & 1u)) >> 16;   // RNE
  return (ushortT)r;
}

static __device__ __forceinline__ bf16x4 pack4(float4 v) {
  bf16x4 r;
  r[0] = (short)f2bf(v.x);
  r[1] = (short)f2bf(v.y);
  r[2] = (short)f2bf(v.z);
  r[3] = (short)f2bf(v.w);
  return r;
}

static __device__ __forceinline__ bf16x8 pack8(float4 lo, float4 hi) {
  bf16x8 bb;
  bb[0] = (short)f2bf(lo.x); bb[1] = (short)f2bf(lo.y);
  bb[2] = (short)f2bf(lo.z); bb[3] = (short)f2bf(lo.w);
  bb[4] = (short)f2bf(hi.x); bb[5] = (short)f2bf(hi.y);
  bb[6] = (short)f2bf(hi.z); bb[7] = (short)f2bf(hi.w);
  return bb;
}

#if __has_builtin(__builtin_amdgcn_mfma_f32_16x16x16bf16_1k)
static __device__ __forceinline__ f32x4 mfma16(bf16x4 a, bf16x4 b, f32x4 c) {
  return __builtin_amdgcn_mfma_f32_16x16x16bf16_1k(a, b, c, 0, 0, 0);
}
#else
static __device__ __forceinline__ f32x4 mfma16(bf16x4 a, bf16x4 b, f32x4 c) {
  f32x4 d;
  asm volatile("v_mfma_f32_16x16x16_bf16 %0, %1, %2, %3"
               : "=v"(d) : "v"(a), "v"(b), "v"(c));
  return d;
}
#endif

static __device__ __forceinline__ f32x4 mfma32(bf16x8 a, bf16x8 b, f32x4 c) {
  return __builtin_amdgcn_mfma_f32_16x16x32_bf16(a, b, c, 0, 0, 0);
}

// v_dot2_f32_bf16: acc += a.lo*b.lo + a.hi*b.hi (bf16 pairs, f32 accum)
static __device__ __forceinline__ void dot2bf(float& acc, unsigned a, unsigned b) {
  asm("v_dot2_f32_bf16 %0, %1, %2, %0" : "+v"(acc) : "v"(a), "v"(b));
}

// ---- setup: prepack W_l + W_e into bf16 MFMA fragments --------------------
__global__ __launch_bounds__(256) void k_setup(const float* __restrict__ Wl,
                                               const float* __restrict__ att_l,
                                               const float* __restrict__ att_r,
                                               const float* __restrict__ We,
                                               const float* __restrict__ att_e,
                                               ushortT* __restrict__ Wlb,
                                               ushortT* __restrict__ Wfb,
                                               ushortT* __restrict__ Web) {
  int tid = threadIdx.x;
  if (blockIdx.x < 16) {
    int gid = blockIdx.x * 256 + tid;      // h*1024 + ct*256 + kt*64 + lane
    int h = gid >> 10, ct = (gid >> 8) & 3, kt = (gid >> 6) & 3, lane = gid & 63;
    int c16 = lane & 15, kg = lane >> 4;
    const float* wp = Wl + (size_t)(h * 64 + ct * 16 + c16) * DIN + kt * 32 + kg * 4;
    bf16x8 bb = pack8(*(const float4*)wp, *(const float4*)(wp + 16));
    *(bf16x8*)(Wlb + (size_t)gid * 8) = bb;
  } else {
    __shared__ float Wf[2][4][128];
    for (int it = 0; it < 4; ++it) {
      int id = it * 256 + tid;             // side*512 + h*128 + k
      int side = id >> 9, h = (id >> 7) & 3, k = id & 127;
      const float* att = side ? att_r : att_l;
      float s = 0.f;
      for (int c = 0; c < 64; ++c)
        s += Wl[(size_t)(h * 64 + c) * DIN + k] * att[h * 64 + c];
      Wf[side][h][k] = s;
    }
    __syncthreads();
    for (int it = 0; it < 4; ++it) {
      int fid = it * 256 + tid;            // h*256 + kt*64 + lane
      int h = fid >> 8, kt = (fid >> 6) & 3, lane = fid & 63;
      int c16 = lane & 15, kg = lane >> 4;
      bf16x8 bb = {};
      if (c16 < 2) {
        const float* p = &Wf[c16][h][kt * 32 + kg * 4];
        bb = pack8(*(const float4*)p, *(const float4*)(p + 16));
      }
      *(bf16x8*)(Wfb + (size_t)fid * 8) = bb;
    }
    if (tid < 64) {
      int lane = tid;
      int col = lane & 15, kg = lane >> 4;
#pragma unroll
      for (int ct = 0; ct < 4; ++ct) {
        float4 wv = *(const float4*)(We + (size_t)(ct * 16 + col) * 16 + kg * 4);
        *(bf16x4*)(Web + (size_t)(ct * 64 + lane) * 4) = pack4(wv);
      }
      float wf0 = 0.f, wf1 = 0.f, wf2 = 0.f, wf3 = 0.f;
      if (col < 4) {
#pragma unroll
        for (int c = 0; c < 16; ++c) {
          float av = att_e[col * 16 + c];
          float4 wv = *(const float4*)(We + (size_t)(col * 16 + c) * 16 + kg * 4);
          wf0 += wv.x * av; wf1 += wv.y * av;
          wf2 += wv.z * av; wf3 += wv.w * av;
        }
      }
      *(bf16x4*)(Web + (size_t)(4 * 64 + lane) * 4) =
          pack4(make_float4(wf0, wf1, wf2, wf3));
    }
  }
}

// ------------- MFMA node projection + fused degree histogram ---------------
__global__ __launch_bounds__(256) void k_nodeproj(const float* __restrict__ x,
                                                  const ushortT* __restrict__ Wlb,
                                                  const ushortT* __restrict__ Wfb,
                                                  const int* __restrict__ eidst,
                                                  int* __restrict__ cnt,
                                                  ushortT* __restrict__ xlb,
                                                  float* __restrict__ al,
                                                  float* __restrict__ ar,
                                                  int N, int E) {
  __shared__ char smem[32 * 264 * 2];            // 16.9KB: staging then out-tile
  ushortT (*Alds)[4][32][8] = (ushortT(*)[4][32][8])smem;   // 8KB used
  ushortT* olds = (ushortT*)smem;                // [32][264]

  int tid = threadIdx.x;
  int w = tid >> 6;          // wave = head
  int lane = tid & 63;
  int c16 = lane & 15;
  int kg = lane >> 4;
  int m0 = blockIdx.x * 32;

  for (int f = tid; f < 32 * 32; f += 256) {
    int r = f >> 5, m = f & 31;
    int gr = m0 + r;
    float4 v = make_float4(0.f, 0.f, 0.f, 0.f);
    if (gr < N) v = *(const float4*)(x + (size_t)gr * DIN + m * 4);
    int kt = m >> 3, half = (m >> 2) & 1, kq = m & 3;
    int rs = r ^ kq ^ ((kt & 1) << 2);
    *(bf16x4*)&Alds[kt][kq][rs][half * 4] = pack4(v);
  }

  f32x4 acc[2][4];
  f32x4 accf[2];
#pragma unroll
  for (int rt = 0; rt < 2; ++rt) {
    accf[rt] = (f32x4){0.f, 0.f, 0.f, 0.f};
#pragma unroll
    for (int ct = 0; ct < 4; ++ct) acc[rt][ct] = (f32x4){0.f, 0.f, 0.f, 0.f};
  }

  __syncthreads();

  const bf16x8* WB = (const bf16x8*)Wlb;
  const bf16x8* WF = (const bf16x8*)Wfb;

#pragma unroll
  for (int kt = 0; kt < 4; ++kt) {
    bf16x8 afr[2];
#pragma unroll
    for (int rt = 0; rt < 2; ++rt) {
      int rs = (rt * 16 + c16) ^ kg ^ ((kt & 1) << 2);
      afr[rt] = *(const bf16x8*)&Alds[kt][kg][rs][0];
    }
#pragma unroll
    for (int ct = 0; ct < 4; ++ct) {
      bf16x8 b = WB[((w * 4 + ct) * 4 + kt) * 64 + lane];
      acc[0][ct] = mfma32(afr[0], b, acc[0][ct]);
      acc[1][ct] = mfma32(afr[1], b, acc[1][ct]);
    }
    bf16x8 bf = WF[(w * 4 + kt) * 64 + lane];
    accf[0] = mfma32(afr[0], bf, accf[0]);
    accf[1] = mfma32(afr[1], bf, accf[1]);
  }

  __syncthreads();   // done reading staging LDS; reuse as out-tile

  if (c16 < 2) {
#pragma unroll
    for (int rt = 0; rt < 2; ++rt) {
#pragma unroll
      for (int reg = 0; reg < 4; ++reg) {
        int gr = m0 + rt * 16 + kg * 4 + reg;
        if (gr < N) {
          if (c16 == 0) al[(size_t)gr * H + w] = accf[rt][reg];
          else          ar[(size_t)gr * H + w] = accf[rt][reg];
        }
      }
    }
  }

#pragma unroll
  for (int rt = 0; rt < 2; ++rt) {
#pragma unroll
    for (int reg = 0; reg < 4; ++reg) {
      int r = rt * 16 + kg * 4 + reg;
#pragma unroll
      for (int ct = 0; ct < 4; ++ct)
        olds[r * 264 + (ct * 16 + c16) * 4 + w] = f2bf(acc[rt][ct][reg]);
    }
  }
  __syncthreads();

  for (int f = tid; f < 32 * 32; f += 256) {
    int r = f >> 5, ch = f & 31;
    int gr = m0 + r;
    if (gr < N) {
      uint4 v = *(const uint4*)&olds[r * 264 + ch * 8];
      *(uint4*)(xlb + (size_t)gr * 256 + ch * 8) = v;
    }
  }

  // ---- fused degree histogram (grid-stride over edges) ----
  int total = gridDim.x * 256;
  for (int e = blockIdx.x * 256 + tid; e < E; e += total)
    atomicAdd(&cnt[eidst[e]], 1);
}

// ---------------- scans ----------------------------------------------------
__global__ __launch_bounds__(256) void k_scan1(const int* __restrict__ cnt,
                                               int* __restrict__ offs,
                                               int* __restrict__ bsum, int N) {
  __shared__ int s[256];
  int i = blockIdx.x * 256 + threadIdx.x;
  int v = (i < N) ? cnt[i] : 0;
  s[threadIdx.x] = v;
  __syncthreads();
  for (int off = 1; off < 256; off <<= 1) {
    int t = (threadIdx.x >= off) ? s[threadIdx.x - off] : 0;
    __syncthreads();
    s[threadIdx.x] += t;
    __syncthreads();
  }
  if (i < N) offs[i] = s[threadIdx.x] - v;
  if (threadIdx.x == 255) bsum[blockIdx.x] = s[255];
}

__global__ __launch_bounds__(256) void k_scan2(const int* __restrict__ bsum,
                                               int* __restrict__ boffs, int NB) {
  __shared__ int s[256];
  int v = (threadIdx.x < NB) ? bsum[threadIdx.x] : 0;
  s[threadIdx.x] = v;
  __syncthreads();
  for (int off = 1; off < 256; off <<= 1) {
    int t = (threadIdx.x >= off) ? s[threadIdx.x - off] : 0;
    __syncthreads();
    s[threadIdx.x] += t;
    __syncthreads();
  }
  if (threadIdx.x < NB) boffs[threadIdx.x] = s[threadIdx.x] - v;
}

__global__ __launch_bounds__(256) void k_scan3(int* __restrict__ offs,
                                               const int* __restrict__ boffs,
                                               int* __restrict__ cursor, int N) {
  int i = blockIdx.x * 256 + threadIdx.x;
  if (i < N) {
    int o = offs[i] + boffs[blockIdx.x];
    offs[i] = o;
    cursor[i] = o;
  }
}

// ---- wave-specialized edge kernel: waves 0-3 GEMM, 4-7 scatter ------------
__global__ __launch_bounds__(512) void k_edgefused(const float* __restrict__ ea,
                                                   const ushortT* __restrict__ Web,
                                                   const float* __restrict__ ebias,
                                                   const int* __restrict__ ei,
                                                   const float* __restrict__ al,
                                                   const float* __restrict__ ar,
                                                   int* __restrict__ cur,
                                                   float* __restrict__ eout,
                                                   uint4* __restrict__ rec, int E) {
  __shared__ float alds[4][4][68];   // [gemm wave][head][local edge], padded
  int tid = threadIdx.x;
  int w = tid >> 6;          // 0..7
  int lane = tid & 63;
  int base = blockIdx.x * 256;

  if (w < 4) {
    // ---------------- GEMM waves ----------------
    int col = lane & 15;
    int kg = lane >> 4;
    const bf16x4* WE = (const bf16x4*)Web;
    bf16x4 bfr0 = WE[0 * 64 + lane];
    bf16x4 bfr1 = WE[1 * 64 + lane];
    bf16x4 bfr2 = WE[2 * 64 + lane];
    bf16x4 bfr3 = WE[3 * 64 + lane];
    bf16x4 bfold = WE[4 * 64 + lane];
    float bias = ebias[col];
    int ebase = base + w * 64;

#pragma unroll
    for (int t = 0; t < 4; ++t) {
      int tb = ebase + t * 16;
      if (tb >= E) continue;
      float4 av = *(const float4*)(ea + (size_t)(tb + col) * EIN + kg * 4);
      bf16x4 afr = pack4(av);
      f32x4 z = {0.f, 0.f, 0.f, 0.f};
      f32x4 d0 = mfma16(afr, bfr0, z);
      f32x4 d1 = mfma16(afr, bfr1, z);
      f32x4 d2 = mfma16(afr, bfr2, z);
      f32x4 d3 = mfma16(afr, bfr3, z);
      f32x4 d4 = mfma16(afr, bfold, z);

#pragma unroll
      for (int reg = 0; reg < 4; ++reg) {
        float m = fmaxf(fmaxf(d0[reg], d1[reg]), fmaxf(d2[reg], d3[reg]));
        eout[(size_t)(tb + kg * 4 + reg) * EOUT + col] = fmaxf(m + bias, 0.f);
      }

      if (col < 4) {
#pragma unroll
        for (int reg = 0; reg < 4; ++reg)
          alds[w][col][t * 16 + kg * 4 + reg] = d4[reg];
      }
    }
    __syncthreads();
  } else {
    // -------- scatter waves: ALL latency ops pre-barrier ------------------
    int ws = w - 4;
    int g = base + ws * 64 + lane;
    int sN = 0, dN = 0, p = 0;
    float4 a4 = make_float4(0.f, 0.f, 0.f, 0.f);
    float4 r4 = make_float4(0.f, 0.f, 0.f, 0.f);
    if (g < E) {
      sN = ei[g];
      dN = ei[E + g];
      a4 = *(const float4*)(al + (size_t)sN * H);     // random; overlaps GEMM
      r4 = *(const float4*)(ar + (size_t)dN * H);
      p = atomicAdd(&cur[dN], 1);                     // round-trip overlaps GEMM
    }
    __syncthreads();
    if (g < E) {
      float lg0 = a4.x + r4.x + alds[ws][0][lane];
      float lg1 = a4.y + r4.y + alds[ws][1][lane];
      float lg2 = a4.z + r4.z + alds[ws][2][lane];
      float lg3 = a4.w + r4.w + alds[ws][3][lane];
      lg0 = (lg0 >= 0.f) ? lg0 : NEG_SLOPE * lg0;
      lg1 = (lg1 >= 0.f) ? lg1 : NEG_SLOPE * lg1;
      lg2 = (lg2 >= 0.f) ? lg2 : NEG_SLOPE * lg2;
      lg3 = (lg3 >= 0.f) ? lg3 : NEG_SLOPE * lg3;
      unsigned ex01 = (unsigned)f2bf(__expf(lg0)) | ((unsigned)f2bf(__expf(lg1)) << 16);
      unsigned ex23 = (unsigned)f2bf(__expf(lg2)) | ((unsigned)f2bf(__expf(lg3)) << 16);
      uint4 v;
      v.x = ex01; v.y = ex23; v.z = ((unsigned)sN) << 9; v.w = 0;  // byte offset
      rec[p] = v;
    }
  }
}

// ------- aggregation: wave per node, 8-wide gathers, v_dot2_f32_bf16 -------
__global__ __launch_bounds__(256) void k_agg(const char* __restrict__ xlbB,
                                             const uint4* __restrict__ rec,
                                             const int* __restrict__ offs,
                                             const int* __restrict__ cnt,
                                             const float* __restrict__ nbias,
                                             float* __restrict__ out, int N) {
  int wv = (blockIdx.x * 256 + threadIdx.x) >> 6;
  int lane = threadIdx.x & 63;
  if (wv >= N) return;
  int deg = cnt[wv];
  int start = offs[wv];
  int loff = lane * 8;
  const unsigned ONES = 0x3F803F80u;   // bf16 {1.0, 1.0}
  float acc0 = 0.f, acc1 = 0.f, acc2 = 0.f, acc3 = 0.f;
  float s0 = 0.f, s1 = 0.f, s2 = 0.f, s3 = 0.f;

  int i = 0;
  for (; i + 7 < deg; i += 8) {
    unsigned zo[8], ex0[8], ex1[8];
#pragma unroll
    for (int j = 0; j < 8; ++j) {
      uint4 r = rec[start + i + j];
      ex0[j] = r.x; ex1[j] = r.y; zo[j] = r.z;
    }
    uint2 u[8];
#pragma unroll
    for (int j = 0; j < 8; ++j)
      u[j] = *(const uint2*)(xlbB + (size_t)zo[j] + loff);
#pragma unroll
    for (int j = 0; j < 8; j += 2) {
      // pair edges (j, j+1): pe_h = {e_h(j), e_h(j+1)}, px_h likewise
      unsigned pe0 = __builtin_amdgcn_perm(ex0[j + 1], ex0[j], 0x05040100u);
      unsigned pe1 = __builtin_amdgcn_perm(ex0[j + 1], ex0[j], 0x07060302u);
      unsigned pe2 = __builtin_amdgcn_perm(ex1[j + 1], ex1[j], 0x05040100u);
      unsigned pe3 = __builtin_amdgcn_perm(ex1[j + 1], ex1[j], 0x07060302u);
      unsigned px0 = __builtin_amdgcn_perm(u[j + 1].x, u[j].x, 0x05040100u);
      unsigned px1 = __builtin_amdgcn_perm(u[j + 1].x, u[j].x, 0x07060302u);
      unsigned px2 = __builtin_amdgcn_perm(u[j + 1].y, u[j].y, 0x05040100u);
      unsigned px3 = __builtin_amdgcn_perm(u[j + 1].y, u[j].y, 0x07060302u);
      dot2bf(acc0, pe0, px0);
      dot2bf(acc1, pe1, px1);
      dot2bf(acc2, pe2, px2);
      dot2bf(acc3, pe3, px3);
      dot2bf(s0, pe0, ONES);
      dot2bf(s1, pe1, ONES);
      dot2bf(s2, pe2, ONES);
      dot2bf(s3, pe3, ONES);
    }
  }
  for (; i + 1 < deg; i += 2) {
    uint4 rA = rec[start + i];
    uint4 rB = rec[start + i + 1];
    uint2 uA = *(const uint2*)(xlbB + (size_t)rA.z + loff);
    uint2 uB = *(const uint2*)(xlbB + (size_t)rB.z + loff);
    unsigned pe0 = __builtin_amdgcn_perm(rB.x, rA.x, 0x05040100u);
    unsigned pe1 = __builtin_amdgcn_perm(rB.x, rA.x, 0x07060302u);
    unsigned pe2 = __builtin_amdgcn_perm(rB.y, rA.y, 0x05040100u);
    unsigned pe3 = __builtin_amdgcn_perm(rB.y, rA.y, 0x07060302u);
    unsigned px0 = __builtin_amdgcn_perm(uB.x, uA.x, 0x05040100u);
    unsigned px1 = __builtin_amdgcn_perm(uB.x, uA.x, 0x07060302u);
    unsigned px2 = __builtin_amdgcn_perm(uB.y, uA.y, 0x05040100u);
    unsigned px3 = __builtin_amdgcn_perm(uB.y, uA.y, 0x07060302u);
    dot2bf(acc0, pe0, px0);
    dot2bf(acc1, pe1, px1);
    dot2bf(acc2, pe2, px2);
    dot2bf(acc3, pe3, px3);
    dot2bf(s0, pe0, ONES);
    dot2bf(s1, pe1, ONES);
    dot2bf(s2, pe2, ONES);
    dot2bf(s3, pe3, ONES);
  }
  if (i < deg) {
    uint4 r = rec[start + i];
    uint2 u = *(const uint2*)(xlbB + (size_t)r.z + loff);
    float e0 = __uint_as_float(r.x << 16);
    float e1 = __uint_as_float(r.x & 0xFFFF0000u);
    float e2 = __uint_as_float(r.y << 16);
    float e3 = __uint_as_float(r.y & 0xFFFF0000u);
    acc0 += e0 * __uint_as_float(u.x << 16);
    acc1 += e1 * __uint_as_float(u.x & 0xFFFF0000u);
    acc2 += e2 * __uint_as_float(u.y << 16);
    acc3 += e3 * __uint_as_float(u.y & 0xFFFF0000u);
    s0 += e0; s1 += e1; s2 += e2; s3 += e3;
  }
  float best = acc0 / (s0 + 1e-16f);
  best = fmaxf(best, acc1 / (s1 + 1e-16f));
  best = fmaxf(best, acc2 / (s2 + 1e-16f));
  best = fmaxf(best, acc3 / (s3 + 1e-16f));
  out[(size_t)wv * DOUT + lane] = fmaxf(best + nbias[lane], 0.f);
}

// ---------------- launcher -------------------------------------------------
extern "C" void kernel_launch(void* const* d_in, const int* in_sizes, int n_in,
                              void* d_out, int out_size, void* d_ws, size_t ws_size,
                              hipStream_t stream) {
  const float* x     = (const float*)d_in[0];
  const float* ea    = (const float*)d_in[1];
  const int*   ei    = (const int*)d_in[2];
  const float* Wl    = (const float*)d_in[3];
  const float* We    = (const float*)d_in[4];
  const float* att_l = (const float*)d_in[5];
  const float* att_r = (const float*)d_in[6];
  const float* att_e = (const float*)d_in[7];
  const float* nbias = (const float*)d_in[8];
  const float* ebias = (const float*)d_in[9];

  int N = in_sizes[0] / DIN;
  int E = in_sizes[1] / EIN;

  float* out  = (float*)d_out;
  float* eout = (float*)d_out + (size_t)N * DOUT;

  char* w = (char*)d_ws;
  auto alloc = [&](size_t bytes) -> void* {
    void* p = (void*)w;
    w += (bytes + 255) & ~(size_t)255;
    return p;
  };
  ushortT* xlb = (ushortT*)alloc((size_t)N * 256 * 2);
  float* al    = (float*)alloc((size_t)N * H * 4);
  float* ar    = (float*)alloc((size_t)N * H * 4);
  ushortT* Wlb = (ushortT*)alloc(4096 * 8 * 2);
  ushortT* Wfb = (ushortT*)alloc(1024 * 8 * 2);
  ushortT* Web = (ushortT*)alloc(5 * 64 * 4 * 2);
  int* cnt     = (int*)alloc((size_t)N * 4);
  int* offs    = (int*)alloc((size_t)N * 4);
  int* cur     = (int*)alloc((size_t)N * 4);
  int* bsum    = (int*)alloc(256 * 4);
  int* boffs   = (int*)alloc(256 * 4);
  uint4* rec   = (uint4*)alloc((size_t)E * 16);

  hipMemsetAsync(cnt, 0, (size_t)N * 4, stream);

  k_setup<<<17, 256, 0, stream>>>(Wl, att_l, att_r, We, att_e, Wlb, Wfb, Web);
  k_nodeproj<<<(N + 31) / 32, 256, 0, stream>>>(x, Wlb, Wfb, ei + E, cnt,
                                                xlb, al, ar, N, E);
  int NB = (N + 255) / 256;
  k_scan1<<<NB, 256, 0, stream>>>(cnt, offs, bsum, N);
  k_scan2<<<1, 256, 0, stream>>>(bsum, boffs, NB);
  k_scan3<<<NB, 256, 0, stream>>>(offs, boffs, cur, N);
  k_edgefused<<<(E + 255) / 256, 512, 0, stream>>>(ea, Web, ebias, ei, al, ar,
                                                   cur, eout, rec, E);
  k_agg<<<(N * 64 + 255) / 256, 256, 0, stream>>>((const char*)xlb, rec, offs, cnt,
                                                  nbias, out, N);
}